// Round 7
// baseline (89.849 us; speedup 1.0000x reference)
//
#include <hip/hip_runtime.h>

#define N_BINS 15
// fl(1/15) as fp32 — matches jnp.linspace's step (absmax 0.0 in R1-R5)
#define INV15 0.066666670143604278564453125f

#define CHUNK_ROWS  128          // rows per wave-chunk
#define CHUNK_BYTES 5120         // per matrix: 128 rows * 40 B

// async global->LDS, 16B per lane; aux=0x2 sets the NT (non-temporal) CPol bit
// (NT broke the ~3.4 TB/s L2/L3 allocate-thrash wall: R4 91us -> R5 65us)
#define GLD16(gaddr, laddr)                                                   \
  __builtin_amdgcn_global_load_lds(                                           \
      (const __attribute__((address_space(1))) void*)(gaddr),                 \
      (__attribute__((address_space(3))) void*)(laddr), 16, 0, 2)

// partials layout in d_ws: float[45][G]; seg 0..14 conf, 15..29 cnt, 30..44 acc
__global__ __launch_bounds__(64, 2) void ece_accum(
    const float* __restrict__ logits,
    const int* __restrict__ labels,
    int N, int G,
    float* __restrict__ partials) {

  __shared__ __align__(16) char s_buf[2][2 * CHUNK_BYTES];   // 20 KB

  float    conf_s[N_BINS];
  unsigned pk_s[N_BINS];   // (count << 16) | acc
#pragma unroll
  for (int b = 0; b < N_BINS; ++b) { conf_s[b] = 0.0f; pk_s[b] = 0u; }

  const int lane = threadIdx.x;            // block == wave
  const int w    = blockIdx.x;
  const int nw   = G;

  // source-side lane permutation: byte-bits[6:4] ^= bits[9:7]  (involution)
  const int swl16 = (((lane & ~7) | ((lane & 7) ^ ((lane >> 3) & 7))) << 4);

  auto issue = [&](int c, int buf) {
    const char* gl = (const char*)logits + (size_t)c * CHUNK_BYTES;
    const char* gb = (const char*)labels + (size_t)c * CHUNK_BYTES;
    char* dl = &s_buf[buf][0];
    char* db = &s_buf[buf][CHUNK_BYTES];
#pragma unroll
    for (int k = 0; k < 5; ++k) {
      GLD16(gl + k * 1024 + swl16, dl + k * 1024);
      GLD16(gb + k * 1024 + swl16, db + k * 1024);
    }
  };

  auto process = [&](const float lg[10], const int lb[10]) {
    float mx   = lg[0];
    int   pred = (lg[0] >= 0.0f) ? 0 : -1;  // sigmoid(x) >= 0.5 <=> x >= 0
    int   best = lb[0];
    int   lidx = 0;
#pragma unroll
    for (int j = 1; j < 10; ++j) {
      mx = fmaxf(mx, lg[j]);
      if (pred < 0 && lg[j] >= 0.0f) pred = j;      // first index of mask-max
      if (lb[j] > best) { best = lb[j]; lidx = j; } // first occurrence of max
    }
    if (pred < 0) pred = 0;

    const float conf = 1.0f / (1.0f + __expf(-mx)); // = max(sigmoid(logits))
    const unsigned pkv = (1u << 16) | ((pred == lidx) ? 1u : 0u);

    int bin = N_BINS - 1;
#pragma unroll
    for (int b = N_BINS - 2; b >= 0; --b) {
      if (conf <= (float)(b + 1) * INV15) bin = b;
    }

#pragma unroll
    for (int b = 0; b < N_BINS; ++b) {
      const bool m = (bin == b);
      conf_s[b] += m ? conf : 0.0f;
      pk_s[b]   += m ? pkv : 0u;
    }
  };

  const int nchunks = N / CHUNK_ROWS;
  int cur = 0;

  if (w < nchunks) issue(w, 0);

  for (int c = w; c < nchunks; c += nw) {
    const int cn = c + nw;
    if (cn < nchunks) {
      issue(cn, cur ^ 1);
      asm volatile("s_waitcnt vmcnt(10)" ::: "memory");  // current chunk done
    } else {
      asm volatile("s_waitcnt vmcnt(0)" ::: "memory");
    }

    // lane processes rows {2*lane, 2*lane+1}: bytes [lane*80, lane*80+80)
    const char* Lc = &s_buf[cur][0];
    float4 f0, f1, f2, f3, f4;
    int4   i0, i1, i2, i3, i4;
#define RD(j, fv, iv)                                                         \
    {                                                                         \
      const int a  = lane * 80 + (j) * 16;                                    \
      const int sa = a ^ (((a >> 7) & 7) << 4);                               \
      fv = *(const float4*)(Lc + sa);                                         \
      iv = *(const int4*)(Lc + CHUNK_BYTES + sa);                             \
    }
    RD(0, f0, i0) RD(1, f1, i1) RD(2, f2, i2) RD(3, f3, i3) RD(4, f4, i4)
#undef RD

    {
      float lg[10] = {f0.x,f0.y,f0.z,f0.w,f1.x,f1.y,f1.z,f1.w,f2.x,f2.y};
      int   lb[10] = {i0.x,i0.y,i0.z,i0.w,i1.x,i1.y,i1.z,i1.w,i2.x,i2.y};
      process(lg, lb);
    }
    {
      float lg[10] = {f2.z,f2.w,f3.x,f3.y,f3.z,f3.w,f4.x,f4.y,f4.z,f4.w};
      int   lb[10] = {i2.z,i2.w,i3.x,i3.y,i3.z,i3.w,i4.x,i4.y,i4.z,i4.w};
      process(lg, lb);
    }
    cur ^= 1;
  }

  // tail rows (N % 128 != 0; none for N=4M) — wave 0, direct global reads
  if (w == 0) {
    for (int r = nchunks * CHUNK_ROWS + lane; r < N; r += 64) {
      float lg[10]; int lb[10];
#pragma unroll
      for (int j = 0; j < 10; ++j) {
        lg[j] = logits[(size_t)r * 10 + j];
        lb[j] = labels[(size_t)r * 10 + j];
      }
      process(lg, lb);
    }
  }

  // wave butterfly reduce; static-indexed stores (no atomics anywhere)
#pragma unroll
  for (int b = 0; b < N_BINS; ++b) {
    float    c = conf_s[b];
    unsigned p = pk_s[b];
#pragma unroll
    for (int off = 32; off > 0; off >>= 1) {
      c += __shfl_xor(c, off, 64);
      p += (unsigned)__shfl_xor((int)p, off, 64);
    }
    if (lane == b) {   // static index b -> stays in VGPRs
      partials[(size_t)b * G + w]                = c;
      partials[(size_t)(N_BINS + b) * G + w]     = (float)(p >> 16);
      partials[(size_t)(2 * N_BINS + b) * G + w] = (float)(p & 0xFFFFu);
    }
  }
}

// Single kernel: 16 waves sum the 45 G-float segments (lane-coalesced),
// then thread 0 computes the final ECE. Replaces reduce_seg + final.
__global__ __launch_bounds__(1024) void ece_reduce_final(
    const float* __restrict__ partials, int G, int N, float* __restrict__ out) {
  __shared__ float s_val[3 * N_BINS];
  const int tid = threadIdx.x;
  const int w = tid >> 6, lane = tid & 63;

  for (int s = w; s < 3 * N_BINS; s += 16) {
    float v = 0.0f;
    for (int i = lane; i < G; i += 64) v += partials[(size_t)s * G + i];
#pragma unroll
    for (int off = 32; off > 0; off >>= 1) v += __shfl_xor(v, off, 64);
    if (lane == 0) s_val[s] = v;
  }
  __syncthreads();

  if (tid == 0) {
    float ece = 0.0f;
    for (int b = 0; b < N_BINS; ++b) {
      const float cnt = s_val[N_BINS + b];
      if (cnt > 0.0f) {
        const float safe = fmaxf(cnt, 1.0f);
        const float gap  = fabsf(s_val[b] / safe - s_val[2 * N_BINS + b] / safe);
        ece += gap * (cnt / (float)N);
      }
    }
    out[0] = ece;
  }
}

extern "C" void kernel_launch(void* const* d_in, const int* in_sizes, int n_in,
                              void* d_out, int out_size, void* d_ws, size_t ws_size,
                              hipStream_t stream) {
  const float* logits = (const float*)d_in[0];
  const int*   labels = (const int*)d_in[1];
  const int N = in_sizes[0] / 10;  // 4,000,000

  // grid = wave count; 2048 = 256 CU x 8 single-wave blocks (LDS-limited)
  int G = (int)(ws_size / (45 * sizeof(float)));
  if (G > 2048) G = 2048;
  if (G < 64)   G = 64;

  float* partials = (float*)d_ws;

  ece_accum<<<G, 64, 0, stream>>>(logits, labels, N, G, partials);
  ece_reduce_final<<<1, 1024, 0, stream>>>(partials, G, N, (float*)d_out);
}

// Round 8
// 71.165 us; speedup vs baseline: 1.2625x; 1.2625x over previous
//
#include <hip/hip_runtime.h>

#define N_BINS 15
// fl(1/15) as fp32 — matches jnp.linspace's step (absmax 0.0 in R1-R6)
#define INV15 0.066666670143604278564453125f

#define CHUNK_ROWS  128          // rows per wave-chunk
#define CHUNK_BYTES 5120         // per matrix: 128 rows * 40 B

// async global->LDS, 16B per lane; aux=0x2 sets the NT (non-temporal) CPol bit
// (NT broke the ~3.4 TB/s L2/L3 allocate-thrash wall: R4 -> R5)
#define GLD16(gaddr, laddr)                                                   \
  __builtin_amdgcn_global_load_lds(                                           \
      (const __attribute__((address_space(1))) void*)(gaddr),                 \
      (__attribute__((address_space(3))) void*)(laddr), 16, 0, 2)

// ws layout: float partials[45][G] | float sums[45] | unsigned counter
__global__ __launch_bounds__(64, 2) void ece_accum(
    const float* __restrict__ logits,
    const int* __restrict__ labels,
    int N, int G,
    float* __restrict__ partials) {

  __shared__ __align__(16) char s_buf[2][2 * CHUNK_BYTES];   // 20 KB

  float    conf_s[N_BINS];
  unsigned pk_s[N_BINS];   // (count << 16) | acc
#pragma unroll
  for (int b = 0; b < N_BINS; ++b) { conf_s[b] = 0.0f; pk_s[b] = 0u; }

  const int lane = threadIdx.x;            // block == wave
  const int w    = blockIdx.x;
  const int nw   = G;

  // source-side lane permutation: byte-bits[6:4] ^= bits[9:7]  (involution)
  const int swl16 = (((lane & ~7) | ((lane & 7) ^ ((lane >> 3) & 7))) << 4);

  auto issue = [&](int c, int buf) {
    const char* gl = (const char*)logits + (size_t)c * CHUNK_BYTES;
    const char* gb = (const char*)labels + (size_t)c * CHUNK_BYTES;
    char* dl = &s_buf[buf][0];
    char* db = &s_buf[buf][CHUNK_BYTES];
#pragma unroll
    for (int k = 0; k < 5; ++k) {
      GLD16(gl + k * 1024 + swl16, dl + k * 1024);
      GLD16(gb + k * 1024 + swl16, db + k * 1024);
    }
  };

  auto process = [&](const float lg[10], const int lb[10]) {
    float mx   = lg[0];
    int   pred = (lg[0] >= 0.0f) ? 0 : -1;  // sigmoid(x) >= 0.5 <=> x >= 0
    int   best = lb[0];
    int   lidx = 0;
#pragma unroll
    for (int j = 1; j < 10; ++j) {
      mx = fmaxf(mx, lg[j]);
      if (pred < 0 && lg[j] >= 0.0f) pred = j;      // first index of mask-max
      if (lb[j] > best) { best = lb[j]; lidx = j; } // first occurrence of max
    }
    if (pred < 0) pred = 0;

    const float conf = 1.0f / (1.0f + __expf(-mx)); // = max(sigmoid(logits))
    const unsigned pkv = (1u << 16) | ((pred == lidx) ? 1u : 0u);

    int bin = N_BINS - 1;
#pragma unroll
    for (int b = N_BINS - 2; b >= 0; --b) {
      if (conf <= (float)(b + 1) * INV15) bin = b;
    }

#pragma unroll
    for (int b = 0; b < N_BINS; ++b) {
      const bool m = (bin == b);
      conf_s[b] += m ? conf : 0.0f;
      pk_s[b]   += m ? pkv : 0u;
    }
  };

  const int nchunks = N / CHUNK_ROWS;
  int cur = 0;

  if (w < nchunks) issue(w, 0);

  for (int c = w; c < nchunks; c += nw) {
    const int cn = c + nw;
    if (cn < nchunks) {
      issue(cn, cur ^ 1);
      asm volatile("s_waitcnt vmcnt(10)" ::: "memory");  // current chunk done
    } else {
      asm volatile("s_waitcnt vmcnt(0)" ::: "memory");
    }

    // lane processes rows {2*lane, 2*lane+1}: bytes [lane*80, lane*80+80)
    const char* Lc = &s_buf[cur][0];
    float4 f0, f1, f2, f3, f4;
    int4   i0, i1, i2, i3, i4;
#define RD(j, fv, iv)                                                         \
    {                                                                         \
      const int a  = lane * 80 + (j) * 16;                                    \
      const int sa = a ^ (((a >> 7) & 7) << 4);                               \
      fv = *(const float4*)(Lc + sa);                                         \
      iv = *(const int4*)(Lc + CHUNK_BYTES + sa);                             \
    }
    RD(0, f0, i0) RD(1, f1, i1) RD(2, f2, i2) RD(3, f3, i3) RD(4, f4, i4)
#undef RD

    {
      float lg[10] = {f0.x,f0.y,f0.z,f0.w,f1.x,f1.y,f1.z,f1.w,f2.x,f2.y};
      int   lb[10] = {i0.x,i0.y,i0.z,i0.w,i1.x,i1.y,i1.z,i1.w,i2.x,i2.y};
      process(lg, lb);
    }
    {
      float lg[10] = {f2.z,f2.w,f3.x,f3.y,f3.z,f3.w,f4.x,f4.y,f4.z,f4.w};
      int   lb[10] = {i2.z,i2.w,i3.x,i3.y,i3.z,i3.w,i4.x,i4.y,i4.z,i4.w};
      process(lg, lb);
    }
    cur ^= 1;
  }

  // tail rows (N % 128 != 0; none for N=4M) — wave 0, direct global reads
  if (w == 0) {
    for (int r = nchunks * CHUNK_ROWS + lane; r < N; r += 64) {
      float lg[10]; int lb[10];
#pragma unroll
      for (int j = 0; j < 10; ++j) {
        lg[j] = logits[(size_t)r * 10 + j];
        lb[j] = labels[(size_t)r * 10 + j];
      }
      process(lg, lb);
    }
  }

  // wave butterfly reduce; static-indexed stores (no atomics in hot path)
#pragma unroll
  for (int b = 0; b < N_BINS; ++b) {
    float    c = conf_s[b];
    unsigned p = pk_s[b];
#pragma unroll
    for (int off = 32; off > 0; off >>= 1) {
      c += __shfl_xor(c, off, 64);
      p += (unsigned)__shfl_xor((int)p, off, 64);
    }
    if (lane == b) {   // static index b -> stays in VGPRs
      partials[(size_t)b * G + w]                = c;
      partials[(size_t)(N_BINS + b) * G + w]     = (float)(p >> 16);
      partials[(size_t)(2 * N_BINS + b) * G + w] = (float)(p & 0xFFFFu);
    }
  }
}

// 45 blocks; block b sums its contiguous G-float segment (coalesced, 45 CUs —
// NOT one block: R6 showed a single-CU strided tail costs ~25 us latency-bound).
// Last-arriving block (fence + device-scope counter) computes the final ECE.
__global__ __launch_bounds__(256) void ece_reduce_seg(
    const float* __restrict__ partials, int G, int N,
    float* __restrict__ sums, unsigned* __restrict__ counter,
    float* __restrict__ out) {
  const int b = blockIdx.x;
  const float* seg = partials + (size_t)b * G;
  float v = 0.0f;
  for (int i = threadIdx.x; i < G; i += 256) v += seg[i];
#pragma unroll
  for (int off = 32; off > 0; off >>= 1) v += __shfl_xor(v, off, 64);

  __shared__ float s[4];
  __shared__ bool  is_last;
  const int wid = threadIdx.x >> 6, lane = threadIdx.x & 63;
  if (lane == 0) s[wid] = v;
  __syncthreads();

  if (threadIdx.x == 0) {
    sums[b] = (s[0] + s[1]) + (s[2] + s[3]);
    __threadfence();                          // release sums[b]
    is_last = (atomicAdd(counter, 1u) == 44u); // device-scope (m20)
  }
  __syncthreads();

  if (is_last) {
    __threadfence();                          // acquire all sums[]
    __shared__ float s_val[3 * N_BINS];
    if (threadIdx.x < 3 * N_BINS) s_val[threadIdx.x] = sums[threadIdx.x]; // parallel
    __syncthreads();
    if (threadIdx.x == 0) {
      float ece = 0.0f;
      for (int k = 0; k < N_BINS; ++k) {
        const float cnt = s_val[N_BINS + k];
        if (cnt > 0.0f) {
          const float safe = fmaxf(cnt, 1.0f);
          const float gap  = fabsf(s_val[k] / safe - s_val[2 * N_BINS + k] / safe);
          ece += gap * (cnt / (float)N);
        }
      }
      out[0] = ece;
    }
  }
}

extern "C" void kernel_launch(void* const* d_in, const int* in_sizes, int n_in,
                              void* d_out, int out_size, void* d_ws, size_t ws_size,
                              hipStream_t stream) {
  const float* logits = (const float*)d_in[0];
  const int*   labels = (const int*)d_in[1];
  const int N = in_sizes[0] / 10;  // 4,000,000

  // grid = wave count; reserve space for sums[45] + counter after partials
  int G = (int)((ws_size - 512) / (45 * sizeof(float)));
  if (G > 2048) G = 2048;
  if (G < 64)   G = 64;

  float*    partials = (float*)d_ws;
  float*    sums     = (float*)((char*)d_ws + (size_t)45 * G * sizeof(float));
  unsigned* counter  = (unsigned*)(sums + 48);   // 16B-aligned slot past sums

  // counter is in poisoned ws and not re-poisoned between replays: zero it
  // on-stream every call (graph-capturable).
  hipMemsetAsync(counter, 0, sizeof(unsigned), stream);

  ece_accum<<<G, 64, 0, stream>>>(logits, labels, N, G, partials);
  ece_reduce_seg<<<45, 256, 0, stream>>>(partials, G, N, sums, counter,
                                         (float*)d_out);
}

// Round 9
// 62.039 us; speedup vs baseline: 1.4483x; 1.1471x over previous
//
#include <hip/hip_runtime.h>

#define N_BINS 15
// fl(1/15) as fp32 — matches jnp.linspace's step (absmax 0.0 in R1-R7)
#define INV15 0.066666670143604278564453125f

#define CHUNK_ROWS  128          // rows per wave-chunk
#define CHUNK_BYTES 5120         // per matrix: 128 rows * 40 B

// async global->LDS, 16B per lane; aux=0x2 sets the NT (non-temporal) CPol bit
// (NT broke the ~3.4 TB/s L2/L3 allocate-thrash wall: R4 91us -> R5 65us)
#define GLD16(gaddr, laddr)                                                   \
  __builtin_amdgcn_global_load_lds(                                           \
      (const __attribute__((address_space(1))) void*)(gaddr),                 \
      (__attribute__((address_space(3))) void*)(laddr), 16, 0, 2)

// ws layout: float partials[45][G] | float sums[48]
__global__ __launch_bounds__(64, 2) void ece_accum(
    const float* __restrict__ logits,
    const int* __restrict__ labels,
    int N, int G,
    float* __restrict__ partials) {

  __shared__ __align__(16) char s_buf[2][2 * CHUNK_BYTES];   // 20 KB -> 8 blk/CU

  float    conf_s[N_BINS];
  unsigned pk_s[N_BINS];   // (count << 16) | acc
#pragma unroll
  for (int b = 0; b < N_BINS; ++b) { conf_s[b] = 0.0f; pk_s[b] = 0u; }

  const int lane = threadIdx.x;            // block == wave
  const int w    = blockIdx.x;
  const int nw   = G;

  // source-side lane permutation: byte-bits[6:4] ^= bits[9:7]  (involution)
  const int swl16 = (((lane & ~7) | ((lane & 7) ^ ((lane >> 3) & 7))) << 4);

  auto issue = [&](int c, int buf) {
    const char* gl = (const char*)logits + (size_t)c * CHUNK_BYTES;
    const char* gb = (const char*)labels + (size_t)c * CHUNK_BYTES;
    char* dl = &s_buf[buf][0];
    char* db = &s_buf[buf][CHUNK_BYTES];
#pragma unroll
    for (int k = 0; k < 5; ++k) {
      GLD16(gl + k * 1024 + swl16, dl + k * 1024);
      GLD16(gb + k * 1024 + swl16, db + k * 1024);
    }
  };

  auto process = [&](const float lg[10], const int lb[10]) {
    float mx   = lg[0];
    int   pred = (lg[0] >= 0.0f) ? 0 : -1;  // sigmoid(x) >= 0.5 <=> x >= 0
    int   best = lb[0];
    int   lidx = 0;
#pragma unroll
    for (int j = 1; j < 10; ++j) {
      mx = fmaxf(mx, lg[j]);
      if (pred < 0 && lg[j] >= 0.0f) pred = j;      // first index of mask-max
      if (lb[j] > best) { best = lb[j]; lidx = j; } // first occurrence of max
    }
    if (pred < 0) pred = 0;

    const float conf = 1.0f / (1.0f + __expf(-mx)); // = max(sigmoid(logits))
    const unsigned pkv = (1u << 16) | ((pred == lidx) ? 1u : 0u);

    int bin = N_BINS - 1;
#pragma unroll
    for (int b = N_BINS - 2; b >= 0; --b) {
      if (conf <= (float)(b + 1) * INV15) bin = b;
    }

#pragma unroll
    for (int b = 0; b < N_BINS; ++b) {
      const bool m = (bin == b);
      conf_s[b] += m ? conf : 0.0f;
      pk_s[b]   += m ? pkv : 0u;
    }
  };

  const int nchunks = N / CHUNK_ROWS;
  int cur = 0;

  if (w < nchunks) issue(w, 0);

  for (int c = w; c < nchunks; c += nw) {
    const int cn = c + nw;
    if (cn < nchunks) {
      issue(cn, cur ^ 1);
      asm volatile("s_waitcnt vmcnt(10)" ::: "memory");  // current chunk done
    } else {
      asm volatile("s_waitcnt vmcnt(0)" ::: "memory");
    }

    // lane processes rows {2*lane, 2*lane+1}: bytes [lane*80, lane*80+80)
    const char* Lc = &s_buf[cur][0];
    float4 f0, f1, f2, f3, f4;
    int4   i0, i1, i2, i3, i4;
#define RD(j, fv, iv)                                                         \
    {                                                                         \
      const int a  = lane * 80 + (j) * 16;                                    \
      const int sa = a ^ (((a >> 7) & 7) << 4);                               \
      fv = *(const float4*)(Lc + sa);                                         \
      iv = *(const int4*)(Lc + CHUNK_BYTES + sa);                             \
    }
    RD(0, f0, i0) RD(1, f1, i1) RD(2, f2, i2) RD(3, f3, i3) RD(4, f4, i4)
#undef RD

    {
      float lg[10] = {f0.x,f0.y,f0.z,f0.w,f1.x,f1.y,f1.z,f1.w,f2.x,f2.y};
      int   lb[10] = {i0.x,i0.y,i0.z,i0.w,i1.x,i1.y,i1.z,i1.w,i2.x,i2.y};
      process(lg, lb);
    }
    {
      float lg[10] = {f2.z,f2.w,f3.x,f3.y,f3.z,f3.w,f4.x,f4.y,f4.z,f4.w};
      int   lb[10] = {i2.z,i2.w,i3.x,i3.y,i3.z,i3.w,i4.x,i4.y,i4.z,i4.w};
      process(lg, lb);
    }
    cur ^= 1;
  }

  // tail rows (N % 128 != 0; none for N=4M) — wave 0, direct global reads
  if (w == 0) {
    for (int r = nchunks * CHUNK_ROWS + lane; r < N; r += 64) {
      float lg[10]; int lb[10];
#pragma unroll
      for (int j = 0; j < 10; ++j) {
        lg[j] = logits[(size_t)r * 10 + j];
        lb[j] = labels[(size_t)r * 10 + j];
      }
      process(lg, lb);
    }
  }

  // wave butterfly reduce; static-indexed stores (no atomics anywhere)
#pragma unroll
  for (int b = 0; b < N_BINS; ++b) {
    float    c = conf_s[b];
    unsigned p = pk_s[b];
#pragma unroll
    for (int off = 32; off > 0; off >>= 1) {
      c += __shfl_xor(c, off, 64);
      p += (unsigned)__shfl_xor((int)p, off, 64);
    }
    if (lane == b) {   // static index b -> stays in VGPRs
      partials[(size_t)b * G + w]                = c;
      partials[(size_t)(N_BINS + b) * G + w]     = (float)(p >> 16);
      partials[(size_t)(2 * N_BINS + b) * G + w] = (float)(p & 0xFFFFu);
    }
  }
}

// 45 blocks; block b sums its contiguous G-float segment — spread over 45 CUs
// (single-CU epilogue is capped at per-CU fabric share ~24 GB/s: R6 lesson).
__global__ __launch_bounds__(256) void ece_reduce_seg(
    const float* __restrict__ partials, int G, float* __restrict__ sums) {
  const int b = blockIdx.x;
  const float* seg = partials + (size_t)b * G;
  float v = 0.0f;
  if ((G & 3) == 0) {
    const float4* seg4 = reinterpret_cast<const float4*>(seg);
    for (int i = threadIdx.x; i < (G >> 2); i += 256) {
      float4 q = seg4[i];
      v += (q.x + q.y) + (q.z + q.w);
    }
  } else {
    for (int i = threadIdx.x; i < G; i += 256) v += seg[i];
  }
#pragma unroll
  for (int off = 32; off > 0; off >>= 1) v += __shfl_xor(v, off, 64);
  __shared__ float s[4];
  const int wid = threadIdx.x >> 6, lane = threadIdx.x & 63;
  if (lane == 0) s[wid] = v;
  __syncthreads();
  if (threadIdx.x == 0) sums[b] = (s[0] + s[1]) + (s[2] + s[3]);
}

// Lane-parallel final: lane b<15 loads its 3 sums concurrently, computes its
// bin's contribution, 4-step shuffle-reduce over lanes 0..15.
__global__ void ece_final(const float* __restrict__ sums, int N,
                          float* __restrict__ out) {
  const int lane = threadIdx.x;
  float contrib = 0.0f;
  if (lane < N_BINS) {
    const float conf = sums[lane];
    const float cnt  = sums[N_BINS + lane];
    const float acc  = sums[2 * N_BINS + lane];
    if (cnt > 0.0f) {
      const float safe = fmaxf(cnt, 1.0f);
      contrib = fabsf(conf / safe - acc / safe) * (cnt / (float)N);
    }
  }
#pragma unroll
  for (int off = 8; off > 0; off >>= 1) contrib += __shfl_xor(contrib, off, 64);
  if (lane == 0) out[0] = contrib;
}

extern "C" void kernel_launch(void* const* d_in, const int* in_sizes, int n_in,
                              void* d_out, int out_size, void* d_ws, size_t ws_size,
                              hipStream_t stream) {
  const float* logits = (const float*)d_in[0];
  const int*   labels = (const int*)d_in[1];
  const int N = in_sizes[0] / 10;  // 4,000,000

  // grid = wave count; 2048 = 256 CU x 8 single-wave blocks (LDS-limited)
  int G = (int)((ws_size - 256) / (45 * sizeof(float)));
  if (G > 2048) G = 2048;
  if (G < 64)   G = 64;

  float* partials = (float*)d_ws;
  float* sums     = (float*)((char*)d_ws + (size_t)45 * G * sizeof(float));

  ece_accum<<<G, 64, 0, stream>>>(logits, labels, N, G, partials);
  ece_reduce_seg<<<45, 256, 0, stream>>>(partials, G, sums);
  ece_final<<<1, 64, 0, stream>>>(sums, N, (float*)d_out);
}